// Round 3
// baseline (34.863 us; speedup 1.0000x reference)
//
#include <hip/hip_runtime.h>

constexpr int A_TOTAL = 5456;
constexpr int BATCH = 16;
constexpr int NUM_CLASSES = 80;
constexpr int NUM_CH = NUM_CLASSES + 2;   // 82
constexpr int MAX_OBJ = 32;
constexpr int LEVELS = 5;
constexpr int BINS = MAX_OBJ * LEVELS;    // 160
constexpr int BLK = 256;
constexpr int QPR = 4;                              // lanes per anchor row
constexpr int TPB_BATCH = A_TOTAL * QPR;            // 21824 threads per batch
constexpr int NBLK_A = (TPB_BATCH + BLK - 1) / BLK; // 86 blocks per batch
constexpr int NBLK_G = (A_TOTAL + BLK - 1) / BLK;   // 22 blocks per batch

__device__ __forceinline__ int lev_of(int a) {
    return (a < 4096) ? 0 : (a < 5120) ? 1 : (a < 5376) ? 2 : (a < 5440) ? 3 : 4;
}

// Kernel A: 4 lanes per anchor row (20 classes each, 64B-granule coalesced),
// shfl-reduce focal within the 4-lane group, lane0 adds GIoU + histogram +
// pos-mask output. Per-block partial histograms (no init, no global atomics).
__global__ void __launch_bounds__(BLK)
loss_accum_kernel(const float* __restrict__ cls_pred,
                  const float* __restrict__ loc_pred,
                  const float* __restrict__ cls_tar,
                  const float* __restrict__ loc_tar,
                  const int*   __restrict__ ind_tar,
                  float* __restrict__ p_sum,   // [B][NBLK_A][BINS]
                  float* __restrict__ p_cnt,   // [B][NBLK_A][BINS]
                  float* __restrict__ out) {
    __shared__ float s_sum[BINS];
    __shared__ float s_cnt[BINS];
    const int t = threadIdx.x;
    for (int i = t; i < BINS; i += BLK) { s_sum[i] = 0.f; s_cnt[i] = 0.f; }
    __syncthreads();

    const int b  = blockIdx.y;
    const int ti = blockIdx.x * BLK + t;   // thread index within batch
    const int a  = ti >> 2;                // anchor row in batch
    const int q  = ti & 3;                 // quarter-row id
    const bool valid = a < A_TOTAL;

    float fl = 0.f;
    size_t row = 0;
    if (valid) {
        row = (size_t)b * A_TOTAL + a;
        const float4* pred4 = (const float4*)cls_pred + row * 20 + q;        // +4 per j
        const float2* tar2  = (const float2*)cls_tar  + row * 41 + 2 * q;    // +8 per j
        #pragma unroll
        for (int j = 0; j < 5; ++j) {
            float4 p4 = pred4[4 * j];
            float2 ta = tar2[8 * j];
            float2 tb = tar2[8 * j + 1];
            float ps[4] = {p4.x, p4.y, p4.z, p4.w};
            float ts[4] = {ta.x, ta.y, tb.x, tb.y};
            #pragma unroll
            for (int k = 0; k < 4; ++k) {
                float p  = fminf(fmaxf(ps[k], 1e-7f), 1.0f - 1e-7f);
                float tt = ts[k];
                float ce = -(tt * __logf(p) + (1.f - tt) * __logf(1.f - p));
                float alpha_t = tt * 0.25f + (1.f - tt) * 0.75f;
                float pt = tt * (1.f - p) + (1.f - tt) * p;
                fl += alpha_t * pt * pt * ce;
            }
        }
    }
    // reduce the 4 quarter-row partials (4-lane groups are wave-aligned)
    fl += __shfl_xor(fl, 1);
    fl += __shfl_xor(fl, 2);

    if (valid && q == 0) {
        float pos = cls_tar[row * NUM_CH + (NUM_CH - 1)];  // L2-hot (covered by row reads)
        out[(size_t)BATCH * A_TOTAL + row] = pos;          // output 1: [B, A]

        float4 T = ((const float4*)(loc_tar  + row * 4))[0];
        float4 P = ((const float4*)(loc_pred + row * 4))[0];
        float area_t = (T.x + T.z) * (T.y + T.w);
        float area_p = (P.x + P.z) * (P.y + P.w);
        float inter  = (fminf(T.x, P.x) + fminf(T.z, P.z)) * (fminf(T.y, P.y) + fminf(T.w, P.w));
        float uni    = area_t + area_p - inter;
        float iou    = inter / fmaxf(uni, 1e-7f);
        float enc    = (fmaxf(T.x, P.x) + fmaxf(T.z, P.z)) * (fmaxf(T.y, P.y) + fmaxf(T.w, P.w));
        float giou   = iou - (enc - uni) / fmaxf(enc, 1e-7f);
        float loss   = fl + (1.f - giou);

        int bin = ind_tar[row] * LEVELS + lev_of(a);
        atomicAdd(&s_sum[bin], loss);
        atomicAdd(&s_cnt[bin], 1.0f);
    }
    __syncthreads();
    const size_t slot = ((size_t)b * NBLK_A + blockIdx.x) * BINS;
    for (int i = t; i < BINS; i += BLK) {
        p_sum[slot + i] = s_sum[i];
        p_cnt[slot + i] = s_cnt[i];
    }
}

// Kernel B: reduce partials (redundantly per block, L2-hot) -> per-(o,l) target
// -> gather to anchors, using pos already staged in d_out by kernel A.
__global__ void __launch_bounds__(BLK)
gather_kernel(const float* __restrict__ p_sum,
              const float* __restrict__ p_cnt,
              const int*   __restrict__ ind_tar,
              const int*   __restrict__ bbox_cnt,
              float* __restrict__ out) {
    __shared__ float s_mean[BINS];
    __shared__ float s_tgt[BINS];
    const int t = threadIdx.x;
    const int b = blockIdx.y;

    if (t < BINS) {
        float s = 0.f, c = 0.f;
        const size_t base = (size_t)b * NBLK_A * BINS + t;
        for (int k = 0; k < NBLK_A; ++k) {
            s += p_sum[base + (size_t)k * BINS];
            c += p_cnt[base + (size_t)k * BINS];
        }
        s_mean[t] = s / fmaxf(1.0f, c);
    }
    __syncthreads();

    if (t < MAX_OBJ) {
        float mean[LEVELS];
        float mx = -1e30f;
        #pragma unroll
        for (int l = 0; l < LEVELS; ++l) {
            mean[l] = s_mean[t * LEVELS + l];
            mx = fmaxf(mx, mean[l]);
        }
        float lmax = mx + 1e-5f;
        float mn = 1e30f;
        #pragma unroll
        for (int l = 0; l < LEVELS; ++l) {
            if (mean[l] == 0.0f) mean[l] = lmax;
            mn = fminf(mn, mean[l]);
        }
        float denom = lmax - mn;
        float tgt[LEVELS];
        float m1 = -1e30f, m2 = -1e30f, m3 = -1e30f;
        #pragma unroll
        for (int l = 0; l < LEVELS; ++l) {
            float v = 1.0f - (mean[l] - mn) / denom;
            tgt[l] = v;
            if (v > m1)      { m3 = m2; m2 = m1; m1 = v; }
            else if (v > m2) { m3 = m2; m2 = v; }
            else if (v > m3) { m3 = v; }
        }
        const bool valid = t < bbox_cnt[b];
        #pragma unroll
        for (int l = 0; l < LEVELS; ++l) {
            float v = tgt[l];
            v = (v >= m3) ? v : 0.0f;
            s_tgt[t * LEVELS + l] = valid ? v : 0.0f;
        }
    }
    __syncthreads();

    const int a = blockIdx.x * BLK + t;
    if (a >= A_TOTAL) return;
    const size_t row = (size_t)b * A_TOTAL + a;
    float pos = out[(size_t)BATCH * A_TOTAL + row];  // staged by kernel A
    int o = ind_tar[row];
    out[row] = (pos > 0.0f) ? s_tgt[o * LEVELS + lev_of(a)] : 1.0f;
}

extern "C" void kernel_launch(void* const* d_in, const int* in_sizes, int n_in,
                              void* d_out, int out_size, void* d_ws, size_t ws_size,
                              hipStream_t stream) {
    const float* cls_pred = (const float*)d_in[0];
    const float* loc_pred = (const float*)d_in[1];
    const float* cls_tar  = (const float*)d_in[2];
    const float* loc_tar  = (const float*)d_in[3];
    const int*   ind_tar  = (const int*)d_in[4];
    const int*   bbox_cnt = (const int*)d_in[5];
    float* out = (float*)d_out;

    float* p_sum = (float*)d_ws;                         // [16][86][160]
    float* p_cnt = p_sum + (size_t)BATCH * NBLK_A * BINS;

    dim3 blk(BLK);
    loss_accum_kernel<<<dim3(NBLK_A, BATCH), blk, 0, stream>>>(
        cls_pred, loc_pred, cls_tar, loc_tar, ind_tar, p_sum, p_cnt, out);
    gather_kernel<<<dim3(NBLK_G, BATCH), blk, 0, stream>>>(
        p_sum, p_cnt, ind_tar, bbox_cnt, out);
}